// Round 4
// baseline (188.755 us; speedup 1.0000x reference)
//
#include <hip/hip_runtime.h>

// MoE: out[b,:] = sum_e softmax(gate(x))[b,e] * (W3_e^T @ relu(W2_e^T @ relu(W1_e^T @ x_b + b1) + b2) + b3)
// Tokens-as-N MFMA. L1 uses 16x16x16 f16 (K=7 useful -> 2-reg frags). L2/L3/gate-L2 use
// 16x16x32 f16 with K-permutation pi(q*8+j)=q*4+(j&3)+16*(j>>2) so C/D layout == next
// layer's B layout in-lane (chaining verified on HW: absmax 0.0156).
// R4: the allocator caps ArchVGPRs at 128 regardless of launch_bounds/waves_per_eu ->
//     fit under it: (a) K=16 L1 frags halve W1F/G1; (b) W2F/W3F/G2 pinned to AGPRs via
//     asm "+a" ties (gfx950 MFMA reads srcA from AGPR). Kills the ~89-dword/thread spill
//     (WRITE_SIZE 53.7MB -> 8.4MB expected).

typedef _Float16 half_t;
typedef _Float16 half2_t __attribute__((ext_vector_type(2)));
typedef _Float16 half4_t __attribute__((ext_vector_type(4)));
typedef _Float16 half8_t __attribute__((ext_vector_type(8)));
typedef __fp16   fp16v2  __attribute__((ext_vector_type(2)));
typedef float  float4_t __attribute__((ext_vector_type(4)));
typedef float  float2_t __attribute__((ext_vector_type(2)));
typedef int    int4_t   __attribute__((ext_vector_type(4)));

#define MFMA_K32(A, B, C) __builtin_amdgcn_mfma_f32_16x16x32_f16((A), (B), (C), 0, 0, 0)
#define MFMA_K16(A, B, C) __builtin_amdgcn_mfma_f32_16x16x16f16((A), (B), (C), 0, 0, 0)

static constexpr int E_ = 8, DIN_ = 6, H_ = 32;

union H8U { half2_t h2[4]; half8_t h8; int4_t i4; };
union H4U { half2_t h2[2]; half4_t h4; };
union HI  { half2_t h; int i; };
union PKU { fp16v2 p; half2_t h; };

__device__ __forceinline__ half2_t pkrtz(float a, float b) {
    PKU u; u.p = __builtin_amdgcn_cvt_pkrtz(a, b);
    return u.h;
}

__device__ __forceinline__ half2_t relu2(half2_t v) {
    const half2_t z = {(_Float16)0.0f, (_Float16)0.0f};
    return __builtin_elementwise_max(v, z);
}

__global__ __launch_bounds__(256)
void moe_kernel(
    const float* __restrict__ x,  const float* __restrict__ W1, const float* __restrict__ b1,
    const float* __restrict__ W2, const float* __restrict__ b2, const float* __restrict__ W3,
    const float* __restrict__ b3, const float* __restrict__ Wg1, const float* __restrict__ bg1,
    const float* __restrict__ Wg2, const float* __restrict__ bg2,
    float* __restrict__ out, int nTiles, int tilesPerWave)
{
    const int tid  = threadIdx.x;
    const int lane = tid & 63;
    const int t    = lane & 15;   // token slot
    const int q    = lane >> 4;   // K-quad
    const int wid  = (int)((blockIdx.x * blockDim.x + tid) >> 6);

    // ---- LDS: b2 bias pairs in pi-order, keyed [e][q] (16-lane broadcast reads, conflict-free)
    __shared__ __align__(16) int b2pk[E_ * 4 * 4];
    for (int idx = tid; idx < E_ * 4 * 4; idx += blockDim.x) {
        int e  = idx >> 4;
        int qq = (idx >> 2) & 3;
        int k  = idx & 3;
        int ch = ((k >> 1) << 4) + qq * 4 + ((k & 1) << 1);   // pi-pair base channel
        HI u; u.h = pkrtz(b2[e * H_ + ch], b2[e * H_ + ch + 1]);
        b2pk[idx] = u.i;
    }
    __syncthreads();

    // ---- L1 A-fragments (K=16, natural k=4q+j; slots 0..5 = features, 6 = bias via 1.0, 7+ = 0)
    half4_t G1[2], W1F[E_][2];
    #pragma unroll
    for (int f = 0; f < 2; ++f) {
        H4U u;
        float v0 = 0.f, v1 = 0.f, v2 = 0.f, v3 = 0.f;
        if (q == 0) {
            v0 = Wg1[0 * H_ + f * 16 + t]; v1 = Wg1[1 * H_ + f * 16 + t];
            v2 = Wg1[2 * H_ + f * 16 + t]; v3 = Wg1[3 * H_ + f * 16 + t];
        } else if (q == 1) {
            v0 = Wg1[4 * H_ + f * 16 + t]; v1 = Wg1[5 * H_ + f * 16 + t];
            v2 = bg1[f * 16 + t];          v3 = 0.f;
        }
        u.h2[0] = pkrtz(v0, v1); u.h2[1] = pkrtz(v2, v3);
        G1[f] = u.h4;
    }
    #pragma unroll
    for (int e = 0; e < E_; ++e) {
        #pragma unroll
        for (int f = 0; f < 2; ++f) {
            H4U u;
            float v0 = 0.f, v1 = 0.f, v2 = 0.f, v3 = 0.f;
            const float* We = W1 + (size_t)e * DIN_ * H_ + f * 16 + t;
            if (q == 0) {
                v0 = We[0 * H_]; v1 = We[1 * H_]; v2 = We[2 * H_]; v3 = We[3 * H_];
            } else if (q == 1) {
                v0 = We[4 * H_]; v1 = We[5 * H_]; v2 = b1[e * H_ + f * 16 + t]; v3 = 0.f;
            }
            u.h2[0] = pkrtz(v0, v1); u.h2[1] = pkrtz(v2, v3);
            W1F[e][f] = u.h4;
        }
    }

    // ---- L2/L3/gate-L2 A-fragments (K=32, pi layout) -> pinned into AGPRs
    H8U G2u, W2Fu[E_][2], W3Fu[E_];
    {
        H8U u;
        #pragma unroll
        for (int p = 0; p < 4; ++p) {
            int c0 = ((p >> 1) << 4) + q * 4 + ((p & 1) << 1);
            float v0 = (t < E_) ? Wg2[c0 * E_ + t] : 0.f;
            float v1 = (t < E_) ? Wg2[(c0 + 1) * E_ + t] : 0.f;
            u.h2[p] = pkrtz(v0, v1);
        }
        G2u = u;
    }
    #pragma unroll
    for (int e = 0; e < E_; ++e) {
        #pragma unroll
        for (int f = 0; f < 2; ++f) {
            H8U u;
            #pragma unroll
            for (int p = 0; p < 4; ++p) {
                int c0 = ((p >> 1) << 4) + q * 4 + ((p & 1) << 1);
                float v0 = W2[(e * H_ + c0) * H_ + f * 16 + t];
                float v1 = W2[(e * H_ + c0 + 1) * H_ + f * 16 + t];
                u.h2[p] = pkrtz(v0, v1);
            }
            W2Fu[e][f] = u;
        }
        {
            H8U u;
            #pragma unroll
            for (int p = 0; p < 4; ++p) {
                int c0 = ((p >> 1) << 4) + q * 4 + ((p & 1) << 1);
                float v0 = 0.f, v1 = 0.f;
                if ((t >> 1) == e) {
                    v0 = W3[(e * H_ + c0) * 2 + (t & 1)];
                    v1 = W3[(e * H_ + c0 + 1) * 2 + (t & 1)];
                }
                u.h2[p] = pkrtz(v0, v1);
            }
            W3Fu[e] = u;
        }
    }
    // Pin the 25 loop-invariant K=32 fragments (100 regs) into the AGPR file; arch VGPRs
    // then hold only L1 frags + temps (~110), under the 128 cap -> no scratch spills.
    #pragma unroll
    for (int e = 0; e < E_; ++e) {
        asm("" : "+a"(W2Fu[e][0].i4));
        asm("" : "+a"(W2Fu[e][1].i4));
        asm("" : "+a"(W3Fu[e].i4));
    }
    asm("" : "+a"(G2u.i4));

    // ---- persistent C-init fragments (biases folded in)
    float4_t bg2F, b3F;
    #pragma unroll
    for (int r = 0; r < 4; ++r) {
        int m = q * 4 + r;
        bg2F[r] = (m < E_) ? bg2[m] : 0.f;
        b3F[r]  = b3[m];
    }
    const float4_t zero4 = {0.f, 0.f, 0.f, 0.f};

    // bpermute byte address for gate distribution: pull from lane (q>>1)*16 + t
    const int gsrc = ((((q >> 1) << 4) | t) << 2);

    const int  tile0 = wid * tilesPerWave;
    const bool ldr   = (lane < 16);

    // all lanes load their token's 6 features (4x same-address replication dedups in L1$)
    const float* xp = x + ((size_t)tile0 * 16 + t) * DIN_;
    float2_t xa = {0.f, 0.f}, xb = {0.f, 0.f}, xc = {0.f, 0.f};
    if (tile0 < nTiles) {
        xa = *(const float2_t*)(xp + 0);
        xb = *(const float2_t*)(xp + 2);
        xc = *(const float2_t*)(xp + 4);
    }

    const half2_t one0  = pkrtz(1.f, 0.f);
    const half2_t zeroh = {(_Float16)0.f, (_Float16)0.f};

    for (int it = 0; it < tilesPerWave; ++it) {
        const int tile = tile0 + it;
        if (tile >= nTiles) break;

        // ---- x B-fragment for K=16 L1: k=4q+j; q0:(x0..x3) q1:(x4,x5,1,0) q2/q3:0
        H4U ux;
        if (q == 0)      { ux.h2[0] = pkrtz(xa[0], xa[1]); ux.h2[1] = pkrtz(xb[0], xb[1]); }
        else if (q == 1) { ux.h2[0] = pkrtz(xc[0], xc[1]); ux.h2[1] = one0; }
        else             { ux.h2[0] = zeroh;               ux.h2[1] = zeroh; }
        const half4_t xB = ux.h4;

        // ---- prefetch next tile's x
        if ((it + 1) < tilesPerWave && (tile + 1) < nTiles) {
            const float* xn = xp + (size_t)(it + 1) * 16 * DIN_;
            xa = *(const float2_t*)(xn + 0);
            xb = *(const float2_t*)(xn + 2);
            xc = *(const float2_t*)(xn + 4);
        }

        // ---- gate
        float4_t hgLo = MFMA_K16(G1[0], xB, zero4);
        float4_t hgHi = MFMA_K16(G1[1], xB, zero4);
        H8U uh;
        uh.h2[0] = relu2(pkrtz(hgLo[0], hgLo[1]));
        uh.h2[1] = relu2(pkrtz(hgLo[2], hgLo[3]));
        uh.h2[2] = relu2(pkrtz(hgHi[0], hgHi[1]));
        uh.h2[3] = relu2(pkrtz(hgHi[2], hgHi[3]));
        float4_t gl = MFMA_K32(G2u.h8, uh.h8, bg2F);

        // ---- softmax over 8 experts (lanes q=0 hold e0..3, q=1 hold e4..7 for token t)
        float mx = fmaxf(fmaxf(gl[0], gl[1]), fmaxf(gl[2], gl[3]));
        mx = fmaxf(mx, __shfl_xor(mx, 16));
        const float L2E = 1.44269504f;
        float mk = mx * L2E;
        float ex0 = __builtin_amdgcn_exp2f(gl[0] * L2E - mk);
        float ex1 = __builtin_amdgcn_exp2f(gl[1] * L2E - mk);
        float ex2 = __builtin_amdgcn_exp2f(gl[2] * L2E - mk);
        float ex3 = __builtin_amdgcn_exp2f(gl[3] * L2E - mk);
        float s = (ex0 + ex1) + (ex2 + ex3);
        s += __shfl_xor(s, 16);
        float rs = __builtin_amdgcn_rcpf(s);
        HI pa, pb;
        pa.h = pkrtz(ex0 * rs, ex1 * rs);
        pb.h = pkrtz(ex2 * rs, ex3 * rs);
        int va = __builtin_amdgcn_ds_bpermute(gsrc, pa.i);
        int vb = __builtin_amdgcn_ds_bpermute(gsrc, pb.i);
        HI gsel; gsel.i = (q & 1) ? vb : va;       // lane(q,t): g[t,2q], g[t,2q+1]
        float ga = (float)gsel.h[0];
        float gb = (float)gsel.h[1];

        // ---- experts
        float4_t Y = b3F;
        #pragma unroll
        for (int e = 0; e < E_; ++e) {
            float4_t lo = MFMA_K16(W1F[e][0], xB, zero4);
            float4_t hi = MFMA_K16(W1F[e][1], xB, zero4);
            H8U u1;
            u1.h2[0] = relu2(pkrtz(lo[0], lo[1]));
            u1.h2[1] = relu2(pkrtz(lo[2], lo[3]));
            u1.h2[2] = relu2(pkrtz(hi[0], hi[1]));
            u1.h2[3] = relu2(pkrtz(hi[2], hi[3]));
            float4_t lo2 = MFMA_K32(W2Fu[e][0].h8, u1.h8, zero4);
            float4_t hi2 = MFMA_K32(W2Fu[e][1].h8, u1.h8, zero4);
            H8U ub; ub.i4 = *(const int4_t*)&b2pk[(e * 4 + q) * 4];   // broadcast read
            H8U u2;
            u2.h2[0] = relu2(pkrtz(lo2[0], lo2[1]) + ub.h2[0]);
            u2.h2[1] = relu2(pkrtz(lo2[2], lo2[3]) + ub.h2[1]);
            u2.h2[2] = relu2(pkrtz(hi2[0], hi2[1]) + ub.h2[2]);
            u2.h2[3] = relu2(pkrtz(hi2[2], hi2[3]) + ub.h2[3]);
            Y = MFMA_K32(W3Fu[e].h8, u2.h8, Y);
        }

        // ---- gated combine: Y rows m=q*4+r are (e=2q+(r>>1), o=r&1); reduce across quads
        float p0 = ga * Y[0] + gb * Y[2];
        float p1 = ga * Y[1] + gb * Y[3];
        p0 += __shfl_xor(p0, 16);
        p0 += __shfl_xor(p0, 32);
        p1 += __shfl_xor(p1, 16);
        p1 += __shfl_xor(p1, 32);
        if (ldr) {
            float2_t o = {p0, p1};
            *(float2_t*)(out + ((size_t)tile * 16 + t) * 2) = o;
        }
    }
}

extern "C" void kernel_launch(void* const* d_in, const int* in_sizes, int n_in,
                              void* d_out, int out_size, void* d_ws, size_t ws_size,
                              hipStream_t stream) {
    const float* x   = (const float*)d_in[0];
    const float* W1  = (const float*)d_in[1];
    const float* b1  = (const float*)d_in[2];
    const float* W2  = (const float*)d_in[3];
    const float* b2  = (const float*)d_in[4];
    const float* W3  = (const float*)d_in[5];
    const float* b3  = (const float*)d_in[6];
    const float* Wg1 = (const float*)d_in[7];
    const float* bg1 = (const float*)d_in[8];
    const float* Wg2 = (const float*)d_in[9];
    const float* bg2 = (const float*)d_in[10];
    float* out = (float*)d_out;

    const int B      = in_sizes[0] / DIN_;
    const int nTiles = (B + 15) / 16;
    const int blocks = 512;
    const int nWaves = blocks * (256 / 64);
    const int tpw    = (nTiles + nWaves - 1) / nWaves;

    moe_kernel<<<blocks, 256, 0, stream>>>(x, W1, b1, W2, b2, W3, b3,
                                           Wg1, bg1, Wg2, bg2, out, nTiles, tpw);
}

// Round 5
// 162.214 us; speedup vs baseline: 1.1636x; 1.1636x over previous
//
#include <hip/hip_runtime.h>

// MoE: out[b,:] = sum_e softmax(gate(x))[b,e] * (W3_e^T @ relu(W2_e^T @ relu(W1_e^T @ x_b + b1) + b2) + b3)
// Tokens-as-N MFMA. L1 uses 16x16x16 f16 (K=7 useful, k=4q+j). L2/L3/gate-L2 use 16x16x32 f16
// with K-permutation pi(q*8+j)=q*4+(j&3)+16*(j>>2) so C/D layout == next layer's B layout
// in-lane (HW-verified: absmax 0.0156).
// R5: wave-specialization by expert. R4 showed one wave holding all 8 experts' weights needs
//     ~290 unified regs -> 1 wave/SIMD -> fully exposed latency (8775 cyc/tile). Now each wave
//     of a 2-wave block holds 4 experts (~116 live regs, waves_per_eu(4) enforces <=128) ->
//     4 waves/SIMD. Gate is recomputed by both waves (+3 cheap MFMAs); partials combined via
//     parity double-buffered LDS with one barrier per tile.

typedef _Float16 half2_t __attribute__((ext_vector_type(2)));
typedef _Float16 half4_t __attribute__((ext_vector_type(4)));
typedef _Float16 half8_t __attribute__((ext_vector_type(8)));
typedef __fp16   fp16v2  __attribute__((ext_vector_type(2)));
typedef float  float4_t __attribute__((ext_vector_type(4)));
typedef float  float2_t __attribute__((ext_vector_type(2)));
typedef int    int4_t   __attribute__((ext_vector_type(4)));

#define MFMA_K32(A, B, C) __builtin_amdgcn_mfma_f32_16x16x32_f16((A), (B), (C), 0, 0, 0)
#define MFMA_K16(A, B, C) __builtin_amdgcn_mfma_f32_16x16x16f16((A), (B), (C), 0, 0, 0)

static constexpr int E_ = 8, DIN_ = 6, H_ = 32, EPW_ = 4;   // experts per wave

union H8U { half2_t h2[4]; half8_t h8; int4_t i4; };
union H4U { half2_t h2[2]; half4_t h4; };
union HI  { half2_t h; int i; };
union PKU { fp16v2 p; half2_t h; };

__device__ __forceinline__ half2_t pkrtz(float a, float b) {
    PKU u; u.p = __builtin_amdgcn_cvt_pkrtz(a, b);
    return u.h;
}

__device__ __forceinline__ half2_t relu2(half2_t v) {
    const half2_t z = {(_Float16)0.0f, (_Float16)0.0f};
    return __builtin_elementwise_max(v, z);
}

__global__ __launch_bounds__(128) __attribute__((amdgpu_waves_per_eu(4)))
void moe_kernel(
    const float* __restrict__ x,  const float* __restrict__ W1, const float* __restrict__ b1,
    const float* __restrict__ W2, const float* __restrict__ b2, const float* __restrict__ W3,
    const float* __restrict__ b3, const float* __restrict__ Wg1, const float* __restrict__ bg1,
    const float* __restrict__ Wg2, const float* __restrict__ bg2,
    float* __restrict__ out, int nTiles, int tilesPerBlock)
{
    const int tid  = threadIdx.x;
    const int lane = tid & 63;
    const int t    = lane & 15;   // token slot
    const int q    = lane >> 4;   // K-quad
    const int wv   = tid >> 6;    // wave in block: 0 or 1
    const int eb   = wv * EPW_;   // this wave's expert base

    // ---- LDS: b2 bias pairs in pi-order keyed [e][q] (broadcast reads), + cross-wave combine buf
    __shared__ __align__(16) int b2pk[E_ * 4 * 4];       // 512 B
    __shared__ float2_t cbuf[2][16];                     // 256 B, parity double-buffered
    if (tid < E_ * 4 * 4) {                              // 128 entries == blockDim
        int e  = tid >> 4;
        int qq = (tid >> 2) & 3;
        int k  = tid & 3;
        int ch = ((k >> 1) << 4) + qq * 4 + ((k & 1) << 1);   // pi-pair base channel
        HI u; u.h = pkrtz(b2[e * H_ + ch], b2[e * H_ + ch + 1]);
        b2pk[tid] = u.i;
    }
    __syncthreads();

    // ---- gate L1 A-fragments (K=16, k=4q+j; slots 0..5 = x features, 6 = bias-as-1.0)
    half4_t G1[2];
    #pragma unroll
    for (int f = 0; f < 2; ++f) {
        H4U u;
        float v0 = 0.f, v1 = 0.f, v2 = 0.f, v3 = 0.f;
        if (q == 0) {
            v0 = Wg1[0 * H_ + f * 16 + t]; v1 = Wg1[1 * H_ + f * 16 + t];
            v2 = Wg1[2 * H_ + f * 16 + t]; v3 = Wg1[3 * H_ + f * 16 + t];
        } else if (q == 1) {
            v0 = Wg1[4 * H_ + f * 16 + t]; v1 = Wg1[5 * H_ + f * 16 + t];
            v2 = bg1[f * 16 + t];          v3 = 0.f;
        }
        u.h2[0] = pkrtz(v0, v1); u.h2[1] = pkrtz(v2, v3);
        G1[f] = u.h4;
    }
    // ---- gate L2 A-fragment (K=32, pi layout)
    half8_t G2;
    {
        H8U u;
        #pragma unroll
        for (int p = 0; p < 4; ++p) {
            int c0 = ((p >> 1) << 4) + q * 4 + ((p & 1) << 1);
            float v0 = (t < E_) ? Wg2[c0 * E_ + t] : 0.f;
            float v1 = (t < E_) ? Wg2[(c0 + 1) * E_ + t] : 0.f;
            u.h2[p] = pkrtz(v0, v1);
        }
        G2 = u.h8;
    }

    // ---- this wave's 4 experts: L1 (K16), L2 (K32 pi), L3 (K32 pi, block-diag rows)
    half4_t W1F[EPW_][2];
    half8_t W2F[EPW_][2], W3F[EPW_];
    #pragma unroll
    for (int j = 0; j < EPW_; ++j) {
        const int e = eb + j;
        #pragma unroll
        for (int f = 0; f < 2; ++f) {
            H4U u;
            float v0 = 0.f, v1 = 0.f, v2 = 0.f, v3 = 0.f;
            const float* We = W1 + (size_t)e * DIN_ * H_ + f * 16 + t;
            if (q == 0)      { v0 = We[0 * H_]; v1 = We[1 * H_]; v2 = We[2 * H_]; v3 = We[3 * H_]; }
            else if (q == 1) { v0 = We[4 * H_]; v1 = We[5 * H_]; v2 = b1[e * H_ + f * 16 + t]; }
            u.h2[0] = pkrtz(v0, v1); u.h2[1] = pkrtz(v2, v3);
            W1F[j][f] = u.h4;
        }
        #pragma unroll
        for (int f = 0; f < 2; ++f) {
            H8U u;
            #pragma unroll
            for (int p = 0; p < 4; ++p) {
                int c0 = ((p >> 1) << 4) + q * 4 + ((p & 1) << 1);
                float v0 = W2[(e * H_ + c0) * H_ + f * 16 + t];
                float v1 = W2[(e * H_ + c0 + 1) * H_ + f * 16 + t];
                u.h2[p] = pkrtz(v0, v1);
            }
            W2F[j][f] = u.h8;
        }
        {
            H8U u;
            #pragma unroll
            for (int p = 0; p < 4; ++p) {
                int c0 = ((p >> 1) << 4) + q * 4 + ((p & 1) << 1);
                float v0 = 0.f, v1 = 0.f;
                if ((t >> 1) == e) {      // Y rows m=(e',o): this expert's rows only
                    v0 = W3[(e * H_ + c0) * 2 + (t & 1)];
                    v1 = W3[(e * H_ + c0 + 1) * 2 + (t & 1)];
                }
                u.h2[p] = pkrtz(v0, v1);
            }
            W3F[j] = u.h8;
        }
    }

    // ---- persistent C-inits: bg2 for the gate; b3 folded into wave0's Y only (added once)
    float4_t bg2F, b3F;
    #pragma unroll
    for (int r = 0; r < 4; ++r) {
        int m = q * 4 + r;
        bg2F[r] = (m < E_) ? bg2[m] : 0.f;
        b3F[r]  = (wv == 0) ? b3[m] : 0.f;
    }
    const float4_t zero4 = {0.f, 0.f, 0.f, 0.f};

    // bpermute byte address for gate distribution: pull from lane (q>>1)*16 + t
    const int gsrc = ((((q >> 1) << 4) | t) << 2);

    const int tile0 = blockIdx.x * tilesPerBlock;

    const float* xp = x + ((size_t)tile0 * 16 + t) * DIN_;
    float2_t xa = {0.f, 0.f}, xb = {0.f, 0.f}, xc = {0.f, 0.f};
    if (tile0 < nTiles) {
        xa = *(const float2_t*)(xp + 0);
        xb = *(const float2_t*)(xp + 2);
        xc = *(const float2_t*)(xp + 4);
    }

    const half2_t one0  = pkrtz(1.f, 0.f);
    const half2_t zeroh = {(_Float16)0.f, (_Float16)0.f};

    for (int it = 0; it < tilesPerBlock; ++it) {
        const int tile = tile0 + it;
        if (tile >= nTiles) break;          // uniform across the block

        // ---- x B-fragment (K=16): k=4q+j; q0:(x0..x3) q1:(x4,x5,1,0) q2/q3:0
        H4U ux;
        if (q == 0)      { ux.h2[0] = pkrtz(xa[0], xa[1]); ux.h2[1] = pkrtz(xb[0], xb[1]); }
        else if (q == 1) { ux.h2[0] = pkrtz(xc[0], xc[1]); ux.h2[1] = one0; }
        else             { ux.h2[0] = zeroh;               ux.h2[1] = zeroh; }
        const half4_t xB = ux.h4;

        // ---- prefetch next tile's x
        if ((it + 1) < tilesPerBlock && (tile + 1) < nTiles) {
            const float* xn = xp + (size_t)(it + 1) * 16 * DIN_;
            xa = *(const float2_t*)(xn + 0);
            xb = *(const float2_t*)(xn + 2);
            xc = *(const float2_t*)(xn + 4);
        }

        // ---- gate (both waves compute it; avoids cross-wave gate traffic)
        float4_t hgLo = MFMA_K16(G1[0], xB, zero4);
        float4_t hgHi = MFMA_K16(G1[1], xB, zero4);
        H8U uh;
        uh.h2[0] = relu2(pkrtz(hgLo[0], hgLo[1]));
        uh.h2[1] = relu2(pkrtz(hgLo[2], hgLo[3]));
        uh.h2[2] = relu2(pkrtz(hgHi[0], hgHi[1]));
        uh.h2[3] = relu2(pkrtz(hgHi[2], hgHi[3]));
        float4_t gl = MFMA_K32(G2, uh.h8, bg2F);

        // ---- softmax over 8 experts (lanes q=0 hold e0..3, q=1 hold e4..7 for token t)
        float mx = fmaxf(fmaxf(gl[0], gl[1]), fmaxf(gl[2], gl[3]));
        mx = fmaxf(mx, __shfl_xor(mx, 16));
        const float L2E = 1.44269504f;
        float mk = mx * L2E;
        float ex0 = __builtin_amdgcn_exp2f(gl[0] * L2E - mk);
        float ex1 = __builtin_amdgcn_exp2f(gl[1] * L2E - mk);
        float ex2 = __builtin_amdgcn_exp2f(gl[2] * L2E - mk);
        float ex3 = __builtin_amdgcn_exp2f(gl[3] * L2E - mk);
        float s = (ex0 + ex1) + (ex2 + ex3);
        s += __shfl_xor(s, 16);
        float rs = __builtin_amdgcn_rcpf(s);
        HI pa, pb;
        pa.h = pkrtz(ex0 * rs, ex1 * rs);
        pb.h = pkrtz(ex2 * rs, ex3 * rs);
        int va = __builtin_amdgcn_ds_bpermute(gsrc, pa.i);
        int vb = __builtin_amdgcn_ds_bpermute(gsrc, pb.i);
        HI gsel; gsel.i = (q & 1) ? vb : va;       // lane(q,t): g[t,2q], g[t,2q+1]
        float ga = (float)gsel.h[0];
        float gb = (float)gsel.h[1];

        // ---- this wave's 4 experts
        float4_t Y = b3F;
        #pragma unroll
        for (int j = 0; j < EPW_; ++j) {
            float4_t lo = MFMA_K16(W1F[j][0], xB, zero4);
            float4_t hi = MFMA_K16(W1F[j][1], xB, zero4);
            H8U u1;
            u1.h2[0] = relu2(pkrtz(lo[0], lo[1]));
            u1.h2[1] = relu2(pkrtz(lo[2], lo[3]));
            u1.h2[2] = relu2(pkrtz(hi[0], hi[1]));
            u1.h2[3] = relu2(pkrtz(hi[2], hi[3]));
            float4_t lo2 = MFMA_K32(W2F[j][0], u1.h8, zero4);
            float4_t hi2 = MFMA_K32(W2F[j][1], u1.h8, zero4);
            H8U ub; ub.i4 = *(const int4_t*)&b2pk[((eb + j) * 4 + q) * 4];   // broadcast
            H8U u2;
            u2.h2[0] = relu2(pkrtz(lo2[0], lo2[1]) + ub.h2[0]);
            u2.h2[1] = relu2(pkrtz(lo2[2], lo2[3]) + ub.h2[1]);
            u2.h2[2] = relu2(pkrtz(hi2[0], hi2[1]) + ub.h2[2]);
            u2.h2[3] = relu2(pkrtz(hi2[2], hi2[3]) + ub.h2[3]);
            Y = MFMA_K32(W3F[j], u2.h8, Y);
        }

        // ---- gated partial: Y rows m=q*4+r are (e=2q+(r>>1), o=r&1); reduce across quads
        float p0 = ga * Y[0] + gb * Y[2];
        float p1 = ga * Y[1] + gb * Y[3];
        p0 += __shfl_xor(p0, 16);
        p0 += __shfl_xor(p0, 32);
        p1 += __shfl_xor(p1, 16);
        p1 += __shfl_xor(p1, 32);

        // ---- cross-wave combine: parity double-buffer + one barrier per tile
        if (wv == 1 && lane < 16) {
            float2_t o = {p0, p1};
            cbuf[it & 1][t] = o;
        }
        __syncthreads();
        if (wv == 0 && lane < 16) {
            float2_t o = cbuf[it & 1][t];
            o[0] += p0; o[1] += p1;
            *(float2_t*)(out + ((size_t)tile * 16 + t) * 2) = o;
        }
    }
}

extern "C" void kernel_launch(void* const* d_in, const int* in_sizes, int n_in,
                              void* d_out, int out_size, void* d_ws, size_t ws_size,
                              hipStream_t stream) {
    const float* x   = (const float*)d_in[0];
    const float* W1  = (const float*)d_in[1];
    const float* b1  = (const float*)d_in[2];
    const float* W2  = (const float*)d_in[3];
    const float* b2  = (const float*)d_in[4];
    const float* W3  = (const float*)d_in[5];
    const float* b3  = (const float*)d_in[6];
    const float* Wg1 = (const float*)d_in[7];
    const float* bg1 = (const float*)d_in[8];
    const float* Wg2 = (const float*)d_in[9];
    const float* bg2 = (const float*)d_in[10];
    float* out = (float*)d_out;

    const int B      = in_sizes[0] / DIN_;
    const int nTiles = (B + 15) / 16;
    const int blocks = 2048;                      // 8 blocks/CU x 2 waves = 16 waves/CU = 4/SIMD
    const int tpb    = (nTiles + blocks - 1) / blocks;

    moe_kernel<<<blocks, 128, 0, stream>>>(x, W1, b1, W2, b2, W3, b3,
                                           Wg1, bg1, Wg2, bg2, out, nTiles, tpb);
}